// Round 4
// baseline (992.418 us; speedup 1.0000x reference)
//
#include <hip/hip_runtime.h>

// GAT (2 layers, heads=1) + 2-layer MLP head. N=100000, E=3200000, D=128.
// R4: bucket-by-dst (128 nodes/bucket) + LDS-accumulator aggregation.
// No per-node CSR, no fp32 global atomics, packed u32 edge records.
// Softmax stabilization uses a GLOBAL upper bound m̄_i = leaky(gmax_asrc + adst_i)
// (valid since leaky_relu is monotone); alpha is mathematically unchanged.

#define NEG 0.2f
#define BSH 7
#define BNODES 128           // nodes per bucket
#define MAXB 800             // >= ceil(100000/128)=782

__device__ __forceinline__ float lrelu(float x) { return x > 0.0f ? x : NEG * x; }

__device__ __forceinline__ unsigned fenc(float f) {
    unsigned u = __float_as_uint(f);
    return (u & 0x80000000u) ? ~u : (u | 0x80000000u);
}
__device__ __forceinline__ float fdec(unsigned e) {
    return (e & 0x80000000u) ? __uint_as_float(e & 0x7FFFFFFFu) : __uint_as_float(~e);
}

// zero gmax[2] and bcnt[NB]
__global__ __launch_bounds__(256) void k_init(unsigned* g, int* bcnt, int NB) {
    int i = blockIdx.x * 256 + threadIdx.x;
    if (i < NB) bcnt[i] = 0;
    if (i < 2) g[i] = 0u;
}

// K1: h1 = x @ W1 (128->16), s1 = h1·a1s, d1 = h1·a1d, gmax1 = max(s1)
__global__ __launch_bounds__(256) void k_gemm1(
    const float* __restrict__ x, const float* __restrict__ W1,
    const float* __restrict__ a1s, const float* __restrict__ a1d,
    float* __restrict__ h1, float* __restrict__ s1, float* __restrict__ d1,
    unsigned* __restrict__ gmax, int N)
{
    __shared__ float sW[128 * 16];
    __shared__ float sx[64 * 132];
    __shared__ float wm[4];
    int tid = threadIdx.x;
    for (int i = tid; i < 2048; i += 256) sW[i] = W1[i];
    int node0 = blockIdx.x * 64;
    for (int i = tid; i < 64 * 32; i += 256) {
        int row = i >> 5, c4 = i & 31;
        int n = node0 + row;
        float4 v = make_float4(0.f, 0.f, 0.f, 0.f);
        if (n < N) v = ((const float4*)x)[(size_t)n * 32 + c4];
        *(float4*)&sx[row * 132 + c4 * 4] = v;
    }
    __syncthreads();

    int node = node0 + (tid >> 2);
    int grp  = tid & 3;
    const float* xr = &sx[(tid >> 2) * 132];
    float4 acc = make_float4(0.f, 0.f, 0.f, 0.f);
#pragma unroll 8
    for (int j = 0; j < 128; ++j) {
        float xv = xr[j];
        float4 w = *(const float4*)&sW[j * 16 + grp * 4];
        acc.x += xv * w.x; acc.y += xv * w.y; acc.z += xv * w.z; acc.w += xv * w.w;
    }
    float4 as = ((const float4*)a1s)[grp];
    float4 ad = ((const float4*)a1d)[grp];
    float sv = acc.x * as.x + acc.y * as.y + acc.z * as.z + acc.w * as.w;
    float dv = acc.x * ad.x + acc.y * ad.y + acc.z * ad.z + acc.w * ad.w;
    sv += __shfl_xor(sv, 1); sv += __shfl_xor(sv, 2);
    dv += __shfl_xor(dv, 1); dv += __shfl_xor(dv, 2);
    if (node < N) {
        *(float4*)&h1[(size_t)node * 16 + grp * 4] = acc;
        if (grp == 0) { s1[node] = sv; d1[node] = dv; }
    }
    float m = (node < N) ? sv : -3.4e38f;
#pragma unroll
    for (int off = 32; off >= 1; off >>= 1) m = fmaxf(m, __shfl_xor(m, off));
    if ((tid & 63) == 0) wm[tid >> 6] = m;
    __syncthreads();
    if (tid == 0) {
        float b = fmaxf(fmaxf(wm[0], wm[1]), fmaxf(wm[2], wm[3]));
        atomicMax(gmax, fenc(b));
    }
}

// bucket histogram, LDS-aggregated
__global__ __launch_bounds__(256) void k_bcount(const int* __restrict__ edst,
                                                int* __restrict__ bcnt, int E, int NB) {
    __shared__ int lc[MAXB];
    int tid = threadIdx.x;
    for (int i = tid; i < NB; i += 256) lc[i] = 0;
    __syncthreads();
    int stride = gridDim.x * 256;
    for (int e = blockIdx.x * 256 + tid; e < E; e += stride)
        atomicAdd(&lc[edst[e] >> BSH], 1);
    __syncthreads();
    for (int i = tid; i < NB; i += 256) { int v = lc[i]; if (v) atomicAdd(&bcnt[i], v); }
}

// exclusive scan of bucket counts -> boffs[NB+1]; init padded cursors
__global__ __launch_bounds__(256) void k_boffs(const int* __restrict__ bcnt,
                                               int* __restrict__ boffs, int* __restrict__ bcur,
                                               int NB, int E) {
    __shared__ int l[MAXB + 1];
    int tid = threadIdx.x;
    for (int i = tid; i < NB; i += 256) l[i] = bcnt[i];
    __syncthreads();
    if (tid == 0) { int run = 0; for (int i = 0; i < NB; ++i) { int c = l[i]; l[i] = run; run += c; } l[NB] = run; }
    __syncthreads();
    for (int i = tid; i < NB; i += 256) { boffs[i] = l[i]; bcur[i * 16] = l[i]; }
    if (tid == 0) boffs[NB] = E;
}

// scatter packed (dstlow<<17 | src) into bucket regions
__global__ __launch_bounds__(256) void k_bscatter(const int* __restrict__ esrc,
                                                  const int* __restrict__ edst,
                                                  int* __restrict__ bcur,
                                                  unsigned* __restrict__ pairs, int E) {
    int e = blockIdx.x * 256 + threadIdx.x;
    if (e >= E) return;
    int d = edst[e], s = esrc[e];
    int pos = atomicAdd(&bcur[(d >> BSH) * 16], 1);
    pairs[pos] = ((unsigned)(d & (BNODES - 1)) << 17) | (unsigned)s;
}

// layer-1 aggregation (LDS accumulators) fused with norm+bias+relu + layer-2 GEMM/scores
__global__ __launch_bounds__(256) void k_agg1(
    const int* __restrict__ boffs, const unsigned* __restrict__ pairs,
    const float* __restrict__ s1, const float* __restrict__ d1, const float* __restrict__ h1,
    const float* __restrict__ b1, const float* __restrict__ W2,
    const float* __restrict__ a2s, const float* __restrict__ a2d,
    float* __restrict__ h2, float* __restrict__ s2, float* __restrict__ d2,
    const unsigned* __restrict__ gmax1p, unsigned* __restrict__ gmax2, int N)
{
    __shared__ float acc[BNODES * 17];
    __shared__ float den[BNODES];
    __shared__ float dds[BNODES], mbs[BNODES];
    __shared__ float sW[160], sb[16], sas[16], sad[16];
    __shared__ float wm[4];
    int tid = threadIdx.x;
    if (tid < 160) sW[tid] = W2[tid];
    if (tid < 16)  sb[tid] = b1[tid];
    if (tid < 10)  { sas[tid] = a2s[tid]; sad[tid] = a2d[tid]; }
    int node0 = blockIdx.x << BSH;
    float g0 = fdec(*gmax1p);
    if (tid < BNODES) {
        int n = node0 + tid;
        float dd = (n < N) ? d1[n] : 0.f;
        dds[tid] = dd; mbs[tid] = lrelu(g0 + dd);
    }
    __syncthreads();
    int g = tid >> 4, k = tid & 15;
    // self loops init accumulators
#pragma unroll
    for (int q = 0; q < 8; ++q) {
        int nl = g * 8 + q, n = node0 + nl;
        if (n < N) {
            float w = __expf(lrelu(s1[n] + dds[nl]) - mbs[nl]);
            acc[nl * 17 + k] = w * h1[(size_t)n * 16 + k];
            if (k == 0) den[nl] = w;
        }
    }
    __syncthreads();
    int j1 = boffs[blockIdx.x + 1];
    for (int j = boffs[blockIdx.x] + g; j < j1; j += 16) {
        unsigned p = pairs[j];
        int src = p & 0x1FFFF, nl = p >> 17;
        float w = __expf(lrelu(s1[src] + dds[nl]) - mbs[nl]);
        atomicAdd(&acc[nl * 17 + k], w * h1[(size_t)src * 16 + k]);
        if (k == 0) atomicAdd(&den[nl], w);
    }
    __syncthreads();
    float sval = -3.4e38f;
#pragma unroll
    for (int q = 0; q < 8; ++q) {
        int nl = g * 8 + q, n = node0 + nl;
        if (n >= N) continue;            // group-uniform
        float inv = 1.f / den[nl];
        float o = fmaxf(acc[nl * 17 + k] * inv + sb[k], 0.f);
        float hh = 0.f;
#pragma unroll
        for (int kk = 0; kk < 16; ++kk) {
            float ov = __shfl(o, kk, 16);
            if (k < 10) hh += ov * sW[kk * 10 + k];
        }
        float ts = (k < 10) ? hh * sas[k] : 0.f;
        float td = (k < 10) ? hh * sad[k] : 0.f;
#pragma unroll
        for (int off = 1; off < 16; off <<= 1) {
            ts += __shfl_xor(ts, off, 16);
            td += __shfl_xor(td, off, 16);
        }
        if (k < 10) h2[(size_t)n * 16 + k] = hh;
        if (k == 0) { s2[n] = ts; d2[n] = td; }
        sval = fmaxf(sval, ts);
    }
    float m = sval;
#pragma unroll
    for (int off = 32; off >= 1; off >>= 1) m = fmaxf(m, __shfl_xor(m, off));
    if ((tid & 63) == 0) wm[tid >> 6] = m;
    __syncthreads();
    if (tid == 0)
        atomicMax(gmax2, fenc(fmaxf(fmaxf(wm[0], wm[1]), fmaxf(wm[2], wm[3]))));
}

// layer-2 aggregation fused with norm+bias + MLP head -> out
__global__ __launch_bounds__(256) void k_agg2(
    const int* __restrict__ boffs, const unsigned* __restrict__ pairs,
    const float* __restrict__ s2, const float* __restrict__ d2, const float* __restrict__ h2,
    const float* __restrict__ b2, const float* __restrict__ Wl1, const float* __restrict__ bl1,
    const float* __restrict__ Wl2, const float* __restrict__ bl2,
    const unsigned* __restrict__ gmax2p, float* __restrict__ out, int N)
{
    __shared__ float acc[BNODES * 17];
    __shared__ float den[BNODES];
    __shared__ float dds[BNODES], mbs[BNODES];
    __shared__ float sW1[100], sb1[16], sW2[16], sb2g[16];
    __shared__ float sbl2;
    int tid = threadIdx.x;
    if (tid < 100) sW1[tid] = Wl1[tid];
    if (tid < 10)  { sb1[tid] = bl1[tid]; sW2[tid] = Wl2[tid]; sb2g[tid] = b2[tid]; }
    if (tid == 0)  sbl2 = bl2[0];
    int node0 = blockIdx.x << BSH;
    float g0 = fdec(*gmax2p);
    if (tid < BNODES) {
        int n = node0 + tid;
        float dd = (n < N) ? d2[n] : 0.f;
        dds[tid] = dd; mbs[tid] = lrelu(g0 + dd);
    }
    __syncthreads();
    int g = tid >> 4, k = tid & 15;
    bool fk = k < 10;
#pragma unroll
    for (int q = 0; q < 8; ++q) {
        int nl = g * 8 + q, n = node0 + nl;
        if (n < N) {
            float w = __expf(lrelu(s2[n] + dds[nl]) - mbs[nl]);
            acc[nl * 17 + k] = fk ? w * h2[(size_t)n * 16 + k] : 0.f;
            if (k == 0) den[nl] = w;
        }
    }
    __syncthreads();
    int j1 = boffs[blockIdx.x + 1];
    for (int j = boffs[blockIdx.x] + g; j < j1; j += 16) {
        unsigned p = pairs[j];
        int src = p & 0x1FFFF, nl = p >> 17;
        float w = __expf(lrelu(s2[src] + dds[nl]) - mbs[nl]);
        if (fk) atomicAdd(&acc[nl * 17 + k], w * h2[(size_t)src * 16 + k]);
        if (k == 0) atomicAdd(&den[nl], w);
    }
    __syncthreads();
#pragma unroll
    for (int q = 0; q < 8; ++q) {
        int nl = g * 8 + q, n = node0 + nl;
        if (n >= N) continue;            // group-uniform
        float inv = 1.f / den[nl];
        float o = fk ? acc[nl * 17 + k] * inv + sb2g[k] : 0.f;
        float v = fk ? sb1[k] : 0.f;
#pragma unroll
        for (int kk = 0; kk < 10; ++kk) {
            float ov = __shfl(o, kk, 16);
            if (fk) v += ov * sW1[kk * 10 + k];
        }
        float t = fmaxf(v, 0.f);
        float c = fk ? t * sW2[k] : 0.f;
#pragma unroll
        for (int off = 1; off < 16; off <<= 1) c += __shfl_xor(c, off, 16);
        if (k == 0) out[n] = c + sbl2;
    }
}

extern "C" void kernel_launch(void* const* d_in, const int* in_sizes, int n_in,
                              void* d_out, int out_size, void* d_ws, size_t ws_size,
                              hipStream_t stream)
{
    const float* x   = (const float*)d_in[0];
    const int*   ei  = (const int*)  d_in[1];   // [2][E] int32
    const float* W1  = (const float*)d_in[2];
    const float* a1s = (const float*)d_in[3];
    const float* a1d = (const float*)d_in[4];
    const float* b1  = (const float*)d_in[5];
    const float* W2  = (const float*)d_in[6];
    const float* a2s = (const float*)d_in[7];
    const float* a2d = (const float*)d_in[8];
    const float* b2  = (const float*)d_in[9];
    const float* Wl1 = (const float*)d_in[10];
    const float* bl1 = (const float*)d_in[11];
    const float* Wl2 = (const float*)d_in[12];
    const float* bl2 = (const float*)d_in[13];

    int N = in_sizes[0] / 128;
    int E = in_sizes[1] / 2;
    const int* ei_src = ei;
    const int* ei_dst = ei + E;
    int NB = (N + BNODES - 1) >> BSH;   // 782 for N=100000 (<= MAXB)

    // ws: 36N+2 floats + (NB+1 + NB + NB*16) ints + E u32  (~27.3 MB)
    size_t need_bytes = ((size_t)N * 36 + 2) * 4 + ((size_t)NB * 18 + 1) * 4 + (size_t)E * 4;
    if (ws_size < need_bytes) return;  // degrade to wrong-answer, never fault

    float*    ws    = (float*)d_ws;
    unsigned* gmax1 = (unsigned*)d_ws;       // [0]
    unsigned* gmax2 = gmax1 + 1;             // [1]
    size_t N16 = (size_t)N * 16;
    float* h1 = ws + 2;                      // N*16
    float* s1 = h1 + N16;                    // N
    float* d1 = s1 + N;                      // N
    float* h2 = d1 + N;                      // N*16 (stride 16, 10 used)
    float* s2 = h2 + N16;                    // N
    float* d2 = s2 + N;                      // N
    int* bcnt  = (int*)(d2 + N);             // NB
    int* boffs = bcnt + NB;                  // NB+1
    int* bcur  = boffs + NB + 1;             // NB*16 (padded: 1 cursor / 64B)
    unsigned* pairs = (unsigned*)(bcur + (size_t)NB * 16);  // E

    int eblk = (E + 255) / 256;

    hipLaunchKernelGGL(k_init, dim3((NB + 255) / 256), dim3(256), 0, stream, gmax1, bcnt, NB);
    hipLaunchKernelGGL(k_gemm1, dim3((N + 63) / 64), dim3(256), 0, stream,
                       x, W1, a1s, a1d, h1, s1, d1, gmax1, N);
    hipLaunchKernelGGL(k_bcount, dim3(256), dim3(256), 0, stream, ei_dst, bcnt, E, NB);
    hipLaunchKernelGGL(k_boffs, dim3(1), dim3(256), 0, stream, bcnt, boffs, bcur, NB, E);
    hipLaunchKernelGGL(k_bscatter, dim3(eblk), dim3(256), 0, stream, ei_src, ei_dst, bcur, pairs, E);
    hipLaunchKernelGGL(k_agg1, dim3(NB), dim3(256), 0, stream,
                       boffs, pairs, s1, d1, h1, b1, W2, a2s, a2d, h2, s2, d2, gmax1, gmax2, N);
    hipLaunchKernelGGL(k_agg2, dim3(NB), dim3(256), 0, stream,
                       boffs, pairs, s2, d2, h2, b2, Wl1, bl1, Wl2, bl2, gmax2, (float*)d_out, N);
}